// Round 1
// baseline (539.301 us; speedup 1.0000x reference)
//
#include <hip/hip_runtime.h>
#include <math.h>

#define NATOMS 10000
#define NEDGES 320000
#define RC_F 5.0f
#define PI_F 3.14159265358979323846f

// ---- workspace layout (in floats) ----
#define WS_SEMB   0        // 12 floats: semb[t][s]
#define WS_W1T    16       // 512:  w1t[j*8+k]  = Wr1[k*64+j]
#define WS_W2T    528      // 3072: w2t[j2*64+k] = Wr2[k*48+j2]
#define WS_CNT    3600     // NATOMS ints
#define WS_OFFS   13600    // NATOMS+1 ints
#define WS_CURSOR 23616    // NATOMS ints
#define WS_STAGE  33664    // NEDGES*52 floats (16B aligned: 33664*4 % 16 == 0, 52*4=208 % 16 == 0)

// multinomial term tables (global component index 0..34)
__device__ __constant__ int   d_PWA[35] = {0, 0,0,1, 0,0,0,1,1,2, 0,0,0,0,1,1,1,2,2,3, 0,0,0,0,0,1,1,1,1,2,2,2,3,3,4};
__device__ __constant__ int   d_PWB[35] = {0, 0,1,0, 0,1,2,0,1,0, 0,1,2,3,0,1,2,0,1,0, 0,1,2,3,4,0,1,2,3,0,1,2,0,1,0};
__device__ __constant__ int   d_PWC[35] = {0, 1,0,0, 2,1,0,1,0,0, 3,2,1,0,2,1,0,1,0,0, 4,3,2,1,0,3,2,1,0,2,1,0,1,0,0};
__device__ __constant__ float d_NM[35]  = {1.f, 1.f,1.f,1.f, 1.f,2.f,1.f,2.f,2.f,1.f,
                                           1.f,3.f,3.f,1.f,3.f,6.f,3.f,3.f,3.f,1.f,
                                           1.f,4.f,6.f,4.f,1.f,4.f,12.f,12.f,4.f,6.f,12.f,6.f,4.f,4.f,1.f};
__device__ __constant__ int   d_LBLK[35]= {0, 1,1,1, 2,2,2,2,2,2, 3,3,3,3,3,3,3,3,3,3, 4,4,4,4,4,4,4,4,4,4,4,4,4,4,4};
__device__ __constant__ int   d_L6[6]   = {0,1,4,10,20,35};

__device__ __forceinline__ float siluf(float x) { return x / (1.0f + expf(-x)); }

__device__ __forceinline__ float psel(float x, int p) {
  float x2 = x * x;
  float r = 1.0f;
  r = (p == 1) ? x : r;
  r = (p == 2) ? x2 : r;
  r = (p == 3) ? x2 * x : r;
  r = (p == 4) ? x2 * x2 : r;
  return r;
}

// ---------------- k_init: zero counters, transpose weights, species embedding ----------------
__global__ void k_init(const float* __restrict__ Wr1, const float* __restrict__ Wr2,
                       const float* __restrict__ Ws1, const float* __restrict__ bs1,
                       const float* __restrict__ Ws2, const float* __restrict__ bs2,
                       float* __restrict__ ws)
{
  int tid = blockIdx.x * blockDim.x + threadIdx.x;
  int* cnt = (int*)(ws + WS_CNT);
  if (tid < NATOMS) cnt[tid] = 0;
  if (tid < 512) { int j = tid >> 3, k = tid & 7;  ws[WS_W1T + tid] = Wr1[k * 64 + j]; }
  if (tid < 3072){ int j = tid >> 6, k = tid & 63; ws[WS_W2T + tid] = Wr2[k * 48 + j]; }
  if (tid < 12) {
    int t = tid >> 2, s = tid & 3;
    float acc = bs2[s];
    for (int j = 0; j < 16; j++) acc += tanhf(Ws1[t * 16 + j] + bs1[j]) * Ws2[j * 4 + s];
    ws[WS_SEMB + tid] = acc;
  }
}

// ---------------- k_hist ----------------
__global__ void k_hist(const int* __restrict__ first_atom, float* __restrict__ ws)
{
  int e = blockIdx.x * blockDim.x + threadIdx.x;
  if (e < NEDGES) {
    int* cnt = (int*)(ws + WS_CNT);
    atomicAdd(&cnt[first_atom[e]], 1);
  }
}

// ---------------- k_scan: single-block exclusive scan of counts ----------------
__global__ __launch_bounds__(1024) void k_scan(float* __restrict__ ws)
{
  const int* cnt = (const int*)(ws + WS_CNT);
  int* offs   = (int*)(ws + WS_OFFS);
  int* cursor = (int*)(ws + WS_CURSOR);
  __shared__ int buf[2][1024];
  __shared__ int s_carry;
  int tid = threadIdx.x;
  if (tid == 0) s_carry = 0;
  __syncthreads();
  for (int base = 0; base < NATOMS; base += 1024) {
    int i = base + tid;
    int v = (i < NATOMS) ? cnt[i] : 0;
    buf[0][tid] = v;
    int pb = 0;
    __syncthreads();
    for (int dstep = 1; dstep < 1024; dstep <<= 1) {
      int val = buf[pb][tid];
      if (tid >= dstep) val += buf[pb][tid - dstep];
      buf[pb ^ 1][tid] = val;
      pb ^= 1;
      __syncthreads();
    }
    int inc = buf[pb][tid];          // inclusive scan of this chunk
    int excl = inc - v + s_carry;
    if (i < NATOMS) { offs[i] = excl; cursor[i] = excl; }
    __syncthreads();
    if (tid == 1023) s_carry += inc;
    __syncthreads();
  }
  if (tid == 0) offs[NATOMS] = s_carry;
}

// ---------------- k_edge: dense per-edge MLP, scatter to sorted slot ----------------
__global__ __launch_bounds__(256) void k_edge(
    const float* __restrict__ rij, const int* __restrict__ species,
    const int* __restrict__ first_atom, const int* __restrict__ second_atom,
    const float* __restrict__ br1, const float* __restrict__ br2,
    float* __restrict__ ws)
{
  int e = blockIdx.x * 256 + threadIdx.x;
  if (e >= NEDGES) return;
  const float* w1t = ws + WS_W1T;
  const float* w2t = ws + WS_W2T;
  int* cursor = (int*)(ws + WS_CURSOR);
  float* stage = ws + WS_STAGE;

  float x = rij[e * 3 + 0], y = rij[e * 3 + 1], z = rij[e * 3 + 2];
  float d = sqrtf(x * x + y * y + z * z + 1e-12f);
  float invd = 1.0f / d;
  float fc = (d < RC_F) ? 0.5f * (cosf(PI_F * d / RC_F) + 1.0f) : 0.0f;

  float bes[8];
  float sq = sqrtf(2.0f / RC_F);
  #pragma unroll
  for (int k = 0; k < 8; k++) bes[k] = sq * sinf((float)(k + 1) * (PI_F / RC_F) * d) * invd;

  float h1[64];
  #pragma unroll
  for (int j = 0; j < 64; j++) {
    float acc = br1[j];
    #pragma unroll
    for (int k = 0; k < 8; k++) acc += bes[k] * w1t[j * 8 + k];
    h1[j] = siluf(acc);
  }

  int a = first_atom[e];
  int pos = atomicAdd(&cursor[a], 1);
  float* eb = stage + (size_t)pos * 52;

  for (int j4 = 0; j4 < 12; j4++) {        // not unrolled: keeps I-cache footprint small
    float v[4];
    #pragma unroll
    for (int u = 0; u < 4; u++) {
      int j2 = j4 * 4 + u;
      float acc = br2[j2];
      #pragma unroll
      for (int k = 0; k < 64; k++) acc += h1[k] * w2t[j2 * 64 + k];
      v[u] = siluf(acc) * fc;
    }
    *(float4*)(eb + j4 * 4) = make_float4(v[0], v[1], v[2], v[3]);
  }
  int t = species[second_atom[e]];
  *(float4*)(eb + 48) = make_float4(x * invd, y * invd, z * invd, __int_as_float(t));
}

// ---------------- k_atom: accumulate G[t][r][c], contract, fused MLP ----------------
__global__ __launch_bounds__(256) void k_atom(
    const float* __restrict__ ws,
    const float* __restrict__ Wa1, const float* __restrict__ ba1,
    const float* __restrict__ Wa2, const float* __restrict__ ba2,
    const float* __restrict__ Wa3, const float* __restrict__ ba3,
    float* __restrict__ out)
{
  __shared__ float sG[3][8][35];   // [t][r][c] : lane-consecutive c -> conflict-free
  __shared__ float sG0[3][8];
  __shared__ float sSemb[12];
  __shared__ float sFeat[192];
  __shared__ float sRed[256];
  __shared__ float sH[64];

  int a = blockIdx.x;
  int tid = threadIdx.x;
  int lane = tid & 63, wv = tid >> 6;

  float* gflat = &sG[0][0][0];
  for (int i = tid; i < 840; i += 256) gflat[i] = 0.0f;
  if (tid < 24) (&sG0[0][0])[tid] = 0.0f;
  if (tid < 12) sSemb[tid] = ws[WS_SEMB + tid];

  const int* offs = (const int*)(ws + WS_OFFS);
  const float* stage = ws + WS_STAGE;
  int start = offs[a], end = offs[a + 1];

  const int c = lane;
  bool isc = (c < 35);
  int pa = 0, pb = 0, pcw = 0, lb = 0;
  if (isc) { pa = d_PWA[c]; pb = d_PWB[c]; pcw = d_PWC[c]; lb = d_LBLK[c]; }
  int rdir = lane - 35;
  bool isd = (rdir >= 0) && (rdir < 8);

  float gc[3][8];
  #pragma unroll
  for (int t2 = 0; t2 < 3; t2++)
    #pragma unroll
    for (int r = 0; r < 8; r++) gc[t2][r] = 0.0f;
  float g0[3] = {0.0f, 0.0f, 0.0f};

  for (int i = start + wv; i < end; i += 4) {
    const float* eb = stage + (size_t)i * 52;
    float4 rt = *(const float4*)(eb + 48);
    int t = __builtin_amdgcn_readfirstlane(__float_as_int(rt.w));
    if (isc) {
      float comp = psel(rt.x, pa) * psel(rt.y, pb) * psel(rt.z, pcw);
      float4 Ra = *(const float4*)(eb + 8 + 8 * lb);
      float4 Rb = *(const float4*)(eb + 12 + 8 * lb);
      float Rl[8] = {Ra.x, Ra.y, Ra.z, Ra.w, Rb.x, Rb.y, Rb.z, Rb.w};
      if (t == 0) {
        #pragma unroll
        for (int r = 0; r < 8; r++) gc[0][r] += comp * Rl[r];
      } else if (t == 1) {
        #pragma unroll
        for (int r = 0; r < 8; r++) gc[1][r] += comp * Rl[r];
      } else {
        #pragma unroll
        for (int r = 0; r < 8; r++) gc[2][r] += comp * Rl[r];
      }
    } else if (isd) {
      float Rr = eb[rdir];
      if (t == 0) g0[0] += Rr; else if (t == 1) g0[1] += Rr; else g0[2] += Rr;
    }
  }
  __syncthreads();   // zeroing (pre-loop) complete everywhere before atomics

  if (isc) {
    #pragma unroll
    for (int t2 = 0; t2 < 3; t2++)
      #pragma unroll
      for (int r = 0; r < 8; r++) atomicAdd(&sG[t2][r][c], gc[t2][r]);
  } else if (isd) {
    #pragma unroll
    for (int t2 = 0; t2 < 3; t2++) atomicAdd(&sG0[t2][rdir], g0[t2]);
  }
  __syncthreads();

  // invariant contraction -> feat[192], layout ((blk*8+r)*4+s)
  if (tid < 192) {
    int s = tid & 3, rr = (tid >> 2) & 7, blk = tid >> 5;
    float se0 = sSemb[s], se1 = sSemb[4 + s], se2 = sSemb[8 + s];
    float f;
    if (blk == 0) {
      f = se0 * sG0[0][rr] + se1 * sG0[1][rr] + se2 * sG0[2][rr];
    } else {
      int c0 = d_L6[blk - 1], c1 = d_L6[blk];
      f = 0.0f;
      for (int cc = c0; cc < c1; cc++) {
        float A = se0 * sG[0][rr][cc] + se1 * sG[1][rr][cc] + se2 * sG[2][rr][cc];
        f += d_NM[cc] * A * A;
      }
    }
    sFeat[tid] = f;
  }
  __syncthreads();

  // MLP layer 1: 192 -> 64, split k over 4 waves
  {
    int j = tid & 63, q = tid >> 6;
    int k0 = q * 48;
    float p = 0.0f;
    #pragma unroll 8
    for (int k = 0; k < 48; k++) p += sFeat[k0 + k] * Wa1[(k0 + k) * 64 + j];
    sRed[tid] = p;
  }
  __syncthreads();
  if (tid < 64) {
    float v = sRed[tid] + sRed[tid + 64] + sRed[tid + 128] + sRed[tid + 192] + ba1[tid];
    sH[tid] = siluf(v);
  }
  __syncthreads();

  // MLP layer 2: 64 -> 64
  {
    int j = tid & 63, q = tid >> 6;
    int k0 = q * 16;
    float p = 0.0f;
    #pragma unroll
    for (int k = 0; k < 16; k++) p += sH[k0 + k] * Wa2[(k0 + k) * 64 + j];
    sRed[tid] = p;
  }
  __syncthreads();

  // layer 3 + output
  if (tid < 64) {
    float v = sRed[tid] + sRed[tid + 64] + sRed[tid + 128] + sRed[tid + 192] + ba2[tid];
    float h2 = siluf(v);
    float pr = h2 * Wa3[tid];
    #pragma unroll
    for (int off = 32; off > 0; off >>= 1) pr += __shfl_down(pr, off, 64);
    if (tid == 0) out[a] = pr + ba3[0];
  }
}

extern "C" void kernel_launch(void* const* d_in, const int* in_sizes, int n_in,
                              void* d_out, int out_size, void* d_ws, size_t ws_size,
                              hipStream_t stream)
{
  const float* rij         = (const float*)d_in[0];
  const int*   species     = (const int*)  d_in[1];
  const int*   first_atom  = (const int*)  d_in[2];
  const int*   second_atom = (const int*)  d_in[3];
  const float* Wr1 = (const float*)d_in[4];
  const float* br1 = (const float*)d_in[5];
  const float* Wr2 = (const float*)d_in[6];
  const float* br2 = (const float*)d_in[7];
  const float* Ws1 = (const float*)d_in[8];
  const float* bs1 = (const float*)d_in[9];
  const float* Ws2 = (const float*)d_in[10];
  const float* bs2 = (const float*)d_in[11];
  const float* Wa1 = (const float*)d_in[12];
  const float* ba1 = (const float*)d_in[13];
  const float* Wa2 = (const float*)d_in[14];
  const float* ba2 = (const float*)d_in[15];
  const float* Wa3 = (const float*)d_in[16];
  const float* ba3 = (const float*)d_in[17];
  float* ws  = (float*)d_ws;
  float* out = (float*)d_out;

  k_init<<<40, 256, 0, stream>>>(Wr1, Wr2, Ws1, bs1, Ws2, bs2, ws);
  k_hist<<<(NEDGES + 255) / 256, 256, 0, stream>>>(first_atom, ws);
  k_scan<<<1, 1024, 0, stream>>>(ws);
  k_edge<<<(NEDGES + 255) / 256, 256, 0, stream>>>(rij, species, first_atom, second_atom, br1, br2, ws);
  k_atom<<<NATOMS, 256, 0, stream>>>(ws, Wa1, ba1, Wa2, ba2, Wa3, ba3, out);
}

// Round 2
// 424.481 us; speedup vs baseline: 1.2705x; 1.2705x over previous
//
#include <hip/hip_runtime.h>
#include <math.h>

#define NATOMS 10000
#define NEDGES 320000
#define RC_F 5.0f
#define PI_F 3.14159265358979323846f

// ---- workspace layout (in floats) ----
#define WS_SEMB   0        // 12 floats: semb[t][s]
#define WS_CNT    3600     // NATOMS ints
#define WS_OFFS   13600    // NATOMS+1 ints
#define WS_CURSOR 23616    // NATOMS ints
#define WS_STAGE  33664    // NEDGES*52 floats (16B aligned)

#define ECHUNK 64          // edges staged in LDS per k_atom iteration

// multinomial term tables (global component index 0..34)
__device__ __constant__ int   d_PWA[35] = {0, 0,0,1, 0,0,0,1,1,2, 0,0,0,0,1,1,1,2,2,3, 0,0,0,0,0,1,1,1,1,2,2,2,3,3,4};
__device__ __constant__ int   d_PWB[35] = {0, 0,1,0, 0,1,2,0,1,0, 0,1,2,3,0,1,2,0,1,0, 0,1,2,3,4,0,1,2,3,0,1,2,0,1,0};
__device__ __constant__ int   d_PWC[35] = {0, 1,0,0, 2,1,0,1,0,0, 3,2,1,0,2,1,0,1,0,0, 4,3,2,1,0,3,2,1,0,2,1,0,1,0,0};
__device__ __constant__ float d_NM[35]  = {1.f, 1.f,1.f,1.f, 1.f,2.f,1.f,2.f,2.f,1.f,
                                           1.f,3.f,3.f,1.f,3.f,6.f,3.f,3.f,3.f,1.f,
                                           1.f,4.f,6.f,4.f,1.f,4.f,12.f,12.f,4.f,6.f,12.f,6.f,4.f,4.f,1.f};
__device__ __constant__ int   d_LBLK[35]= {0, 1,1,1, 2,2,2,2,2,2, 3,3,3,3,3,3,3,3,3,3, 4,4,4,4,4,4,4,4,4,4,4,4,4,4,4};
__device__ __constant__ int   d_L6[6]   = {0,1,4,10,20,35};

__device__ __forceinline__ float siluf(float x) { return x / (1.0f + __expf(-x)); }

__device__ __forceinline__ float psel(float x, int p) {
  float x2 = x * x;
  float r = 1.0f;
  r = (p == 1) ? x : r;
  r = (p == 2) ? x2 : r;
  r = (p == 3) ? x2 * x : r;
  r = (p == 4) ? x2 * x2 : r;
  return r;
}

// ---------------- k_init: zero counters, species embedding ----------------
__global__ void k_init(const float* __restrict__ Ws1, const float* __restrict__ bs1,
                       const float* __restrict__ Ws2, const float* __restrict__ bs2,
                       float* __restrict__ ws)
{
  int tid = blockIdx.x * blockDim.x + threadIdx.x;
  int* cnt = (int*)(ws + WS_CNT);
  if (tid < NATOMS) cnt[tid] = 0;
  if (tid < 12) {
    int t = tid >> 2, s = tid & 3;
    float acc = bs2[s];
    for (int j = 0; j < 16; j++) acc += tanhf(Ws1[t * 16 + j] + bs1[j]) * Ws2[j * 4 + s];
    ws[WS_SEMB + tid] = acc;
  }
}

// ---------------- k_hist ----------------
__global__ void k_hist(const int* __restrict__ first_atom, float* __restrict__ ws)
{
  int e = blockIdx.x * blockDim.x + threadIdx.x;
  if (e < NEDGES) {
    int* cnt = (int*)(ws + WS_CNT);
    atomicAdd(&cnt[first_atom[e]], 1);
  }
}

// ---------------- k_scan: single-block scan, 40 atoms/thread + shuffle scan ----------------
__global__ __launch_bounds__(256) void k_scan(float* __restrict__ ws)
{
  const int* cnt = (const int*)(ws + WS_CNT);
  int* offs   = (int*)(ws + WS_OFFS);
  int* cursor = (int*)(ws + WS_CURSOR);
  __shared__ int wsum[4];
  int tid = threadIdx.x;
  int lane = tid & 63, wv = tid >> 6;
  const int PER = (NATOMS + 255) / 256;   // 40
  int lo = tid * PER;
  int hi = lo + PER; if (hi > NATOMS) hi = NATOMS;
  int s = 0;
  for (int i = lo; i < hi; i++) s += cnt[i];
  int inc = s;
  #pragma unroll
  for (int d = 1; d < 64; d <<= 1) {
    int v = __shfl_up(inc, d, 64);
    if (lane >= d) inc += v;
  }
  if (lane == 63) wsum[wv] = inc;
  __syncthreads();
  int woff = 0;
  for (int w = 0; w < wv; w++) woff += wsum[w];
  int run = woff + inc - s;               // exclusive prefix
  for (int i = lo; i < hi; i++) { int c = cnt[i]; offs[i] = run; cursor[i] = run; run += c; }
  if (tid == 255) offs[NATOMS] = run;
}

// ---------------- k_edge: dense per-edge MLP, scatter to sorted slot ----------------
// Weights passed as const __restrict__ and indexed wave-uniformly -> scalar s_load
// + v_fmac with SGPR operand (weights ride the scalar pipe, VMEM stays free).
__global__ __launch_bounds__(256) void k_edge(
    const float* __restrict__ rij, const int* __restrict__ species,
    const int* __restrict__ first_atom, const int* __restrict__ second_atom,
    const float* __restrict__ Wr1, const float* __restrict__ br1,
    const float* __restrict__ Wr2, const float* __restrict__ br2,
    float* __restrict__ ws)
{
  int e = blockIdx.x * 256 + threadIdx.x;
  if (e >= NEDGES) return;
  int* cursor = (int*)(ws + WS_CURSOR);
  float* stage = ws + WS_STAGE;

  // issue the gather + atomic early so latency overlaps the MLP
  int a = first_atom[e];
  int t = species[second_atom[e]];
  int pos = atomicAdd(&cursor[a], 1);

  float x = rij[e * 3 + 0], y = rij[e * 3 + 1], z = rij[e * 3 + 2];
  float d = sqrtf(x * x + y * y + z * z + 1e-12f);
  float invd = 1.0f / d;
  float fc = (d < RC_F) ? 0.5f * (__cosf(PI_F * d / RC_F) + 1.0f) : 0.0f;

  float bes[8];
  float sq = sqrtf(2.0f / RC_F);
  #pragma unroll
  for (int k = 0; k < 8; k++) bes[k] = sq * __sinf((float)(k + 1) * (PI_F / RC_F) * d) * invd;

  // layer 1: 8 -> 64.  Wr1 is [k=8][j=64]; 4 consecutive j -> s_load_dwordx4
  float h1[64];
  #pragma unroll
  for (int j4 = 0; j4 < 16; j4++) {
    float acc[4];
    #pragma unroll
    for (int u = 0; u < 4; u++) acc[u] = br1[j4 * 4 + u];
    #pragma unroll
    for (int k = 0; k < 8; k++) {
      #pragma unroll
      for (int u = 0; u < 4; u++) acc[u] += bes[k] * Wr1[k * 64 + j4 * 4 + u];
    }
    #pragma unroll
    for (int u = 0; u < 4; u++) h1[j4 * 4 + u] = siluf(acc[u]);
  }

  float* eb = stage + (size_t)pos * 52;

  // layer 2: 64 -> 48.  Wr2 is [k=64][j2=48]; 4 consecutive j2 -> s_load_dwordx4
  for (int j4 = 0; j4 < 12; j4++) {
    float acc[4];
    #pragma unroll
    for (int u = 0; u < 4; u++) acc[u] = br2[j4 * 4 + u];
    #pragma unroll
    for (int k = 0; k < 64; k++) {
      #pragma unroll
      for (int u = 0; u < 4; u++) acc[u] += h1[k] * Wr2[k * 48 + j4 * 4 + u];
    }
    float v0 = siluf(acc[0]) * fc, v1 = siluf(acc[1]) * fc;
    float v2 = siluf(acc[2]) * fc, v3 = siluf(acc[3]) * fc;
    *(float4*)(eb + j4 * 4) = make_float4(v0, v1, v2, v3);
  }
  *(float4*)(eb + 48) = make_float4(x * invd, y * invd, z * invd, __int_as_float(t));
}

// ---------------- k_atom: LDS-stage edges, accumulate G, contract, fused MLP ----------------
__global__ __launch_bounds__(256) void k_atom(
    const float* __restrict__ ws,
    const float* __restrict__ Wa1, const float* __restrict__ ba1,
    const float* __restrict__ Wa2, const float* __restrict__ ba2,
    const float* __restrict__ Wa3, const float* __restrict__ ba3,
    float* __restrict__ out)
{
  __shared__ __align__(16) float sE[ECHUNK * 52];   // 13.3 KB staged edge records
  __shared__ float sG[3][8][35];
  __shared__ float sG0[3][8];
  __shared__ float sSemb[12];
  __shared__ float sFeat[192];
  __shared__ float sRed[256];
  __shared__ float sH[64];

  int a = blockIdx.x;
  int tid = threadIdx.x;
  int lane = tid & 63, wv = tid >> 6;

  float* gflat = &sG[0][0][0];
  for (int i = tid; i < 840; i += 256) gflat[i] = 0.0f;
  if (tid < 24) (&sG0[0][0])[tid] = 0.0f;
  if (tid < 12) sSemb[tid] = ws[WS_SEMB + tid];

  const int* offs = (const int*)(ws + WS_OFFS);
  const float* stage = ws + WS_STAGE;
  int start = offs[a], end = offs[a + 1];

  const int c = lane;
  bool isc = (c < 35);
  int pa = 0, pb = 0, pcw = 0, lb = 0;
  if (isc) { pa = d_PWA[c]; pb = d_PWB[c]; pcw = d_PWC[c]; lb = d_LBLK[c]; }
  int rdir = lane - 35;
  bool isd = (rdir >= 0) && (rdir < 8);

  float gc[3][8];
  #pragma unroll
  for (int t2 = 0; t2 < 3; t2++)
    #pragma unroll
    for (int r = 0; r < 8; r++) gc[t2][r] = 0.0f;
  float g0[3] = {0.0f, 0.0f, 0.0f};

  for (int base = start; base < end; base += ECHUNK) {
    int n = end - base; if (n > ECHUNK) n = ECHUNK;
    __syncthreads();   // previous chunk fully consumed before overwrite
    const float4* src = (const float4*)(stage + (size_t)base * 52);
    float4* dst = (float4*)sE;
    for (int i = tid; i < n * 13; i += 256) dst[i] = src[i];   // coalesced 16B/lane
    __syncthreads();
    for (int i = wv; i < n; i += 4) {
      const float* eb = sE + i * 52;
      float4 rt = *(const float4*)(eb + 48);
      int t = __builtin_amdgcn_readfirstlane(__float_as_int(rt.w));
      if (isc) {
        float comp = psel(rt.x, pa) * psel(rt.y, pb) * psel(rt.z, pcw);
        float4 Ra = *(const float4*)(eb + 8 + 8 * lb);
        float4 Rb = *(const float4*)(eb + 12 + 8 * lb);
        float Rl[8] = {Ra.x, Ra.y, Ra.z, Ra.w, Rb.x, Rb.y, Rb.z, Rb.w};
        if (t == 0) {
          #pragma unroll
          for (int r = 0; r < 8; r++) gc[0][r] += comp * Rl[r];
        } else if (t == 1) {
          #pragma unroll
          for (int r = 0; r < 8; r++) gc[1][r] += comp * Rl[r];
        } else {
          #pragma unroll
          for (int r = 0; r < 8; r++) gc[2][r] += comp * Rl[r];
        }
      } else if (isd) {
        float Rr = eb[rdir];
        if (t == 0) g0[0] += Rr; else if (t == 1) g0[1] += Rr; else g0[2] += Rr;
      }
    }
  }
  __syncthreads();   // zero-fill + loop complete everywhere before atomics

  if (isc) {
    #pragma unroll
    for (int t2 = 0; t2 < 3; t2++)
      #pragma unroll
      for (int r = 0; r < 8; r++) atomicAdd(&sG[t2][r][c], gc[t2][r]);
  } else if (isd) {
    #pragma unroll
    for (int t2 = 0; t2 < 3; t2++) atomicAdd(&sG0[t2][rdir], g0[t2]);
  }
  __syncthreads();

  // invariant contraction -> feat[192], layout ((blk*8+r)*4+s)
  if (tid < 192) {
    int s = tid & 3, rr = (tid >> 2) & 7, blk = tid >> 5;
    float se0 = sSemb[s], se1 = sSemb[4 + s], se2 = sSemb[8 + s];
    float f;
    if (blk == 0) {
      f = se0 * sG0[0][rr] + se1 * sG0[1][rr] + se2 * sG0[2][rr];
    } else {
      int c0 = d_L6[blk - 1], c1 = d_L6[blk];
      f = 0.0f;
      for (int cc = c0; cc < c1; cc++) {
        float A = se0 * sG[0][rr][cc] + se1 * sG[1][rr][cc] + se2 * sG[2][rr][cc];
        f += d_NM[cc] * A * A;
      }
    }
    sFeat[tid] = f;
  }
  __syncthreads();

  // MLP layer 1: 192 -> 64, split k over 4 waves
  {
    int j = tid & 63, q = tid >> 6;
    int k0 = q * 48;
    float p = 0.0f;
    #pragma unroll 8
    for (int k = 0; k < 48; k++) p += sFeat[k0 + k] * Wa1[(k0 + k) * 64 + j];
    sRed[tid] = p;
  }
  __syncthreads();
  if (tid < 64) {
    float v = sRed[tid] + sRed[tid + 64] + sRed[tid + 128] + sRed[tid + 192] + ba1[tid];
    sH[tid] = siluf(v);
  }
  __syncthreads();

  // MLP layer 2: 64 -> 64
  {
    int j = tid & 63, q = tid >> 6;
    int k0 = q * 16;
    float p = 0.0f;
    #pragma unroll
    for (int k = 0; k < 16; k++) p += sH[k0 + k] * Wa2[(k0 + k) * 64 + j];
    sRed[tid] = p;
  }
  __syncthreads();

  // layer 3 + output
  if (tid < 64) {
    float v = sRed[tid] + sRed[tid + 64] + sRed[tid + 128] + sRed[tid + 192] + ba2[tid];
    float h2 = siluf(v);
    float pr = h2 * Wa3[tid];
    #pragma unroll
    for (int off = 32; off > 0; off >>= 1) pr += __shfl_down(pr, off, 64);
    if (tid == 0) out[a] = pr + ba3[0];
  }
}

extern "C" void kernel_launch(void* const* d_in, const int* in_sizes, int n_in,
                              void* d_out, int out_size, void* d_ws, size_t ws_size,
                              hipStream_t stream)
{
  const float* rij         = (const float*)d_in[0];
  const int*   species     = (const int*)  d_in[1];
  const int*   first_atom  = (const int*)  d_in[2];
  const int*   second_atom = (const int*)  d_in[3];
  const float* Wr1 = (const float*)d_in[4];
  const float* br1 = (const float*)d_in[5];
  const float* Wr2 = (const float*)d_in[6];
  const float* br2 = (const float*)d_in[7];
  const float* Ws1 = (const float*)d_in[8];
  const float* bs1 = (const float*)d_in[9];
  const float* Ws2 = (const float*)d_in[10];
  const float* bs2 = (const float*)d_in[11];
  const float* Wa1 = (const float*)d_in[12];
  const float* ba1 = (const float*)d_in[13];
  const float* Wa2 = (const float*)d_in[14];
  const float* ba2 = (const float*)d_in[15];
  const float* Wa3 = (const float*)d_in[16];
  const float* ba3 = (const float*)d_in[17];
  float* ws  = (float*)d_ws;
  float* out = (float*)d_out;

  k_init<<<40, 256, 0, stream>>>(Ws1, bs1, Ws2, bs2, ws);
  k_hist<<<(NEDGES + 255) / 256, 256, 0, stream>>>(first_atom, ws);
  k_scan<<<1, 256, 0, stream>>>(ws);
  k_edge<<<(NEDGES + 255) / 256, 256, 0, stream>>>(rij, species, first_atom, second_atom,
                                                   Wr1, br1, Wr2, br2, ws);
  k_atom<<<NATOMS, 256, 0, stream>>>(ws, Wa1, ba1, Wa2, ba2, Wa3, ba3, out);
}

// Round 3
// 342.734 us; speedup vs baseline: 1.5735x; 1.2385x over previous
//
#include <hip/hip_runtime.h>
#include <math.h>

#define NATOMS 10000
#define NEDGES 320000
#define NBINS  (NATOMS * 4)     // bin = atom*4 + species (bin a*4+3 always empty)
#define RC_F 5.0f
#define PI_F 3.14159265358979323846f

// ---- workspace layout (in floats) ----
#define WS_SEMB   0         // 12 floats: semb[t][s]
#define WS_CNT    16        // NBINS ints
#define WS_OFFS   40016     // NBINS+1 ints
#define WS_CURSOR 80024     // NBINS ints
#define WS_STAGE  120032    // NEDGES*52 floats (base 16B aligned, stride 208B)

// multinomial term tables (global component index 0..34)
__device__ __constant__ int   d_PWA[35] = {0, 0,0,1, 0,0,0,1,1,2, 0,0,0,0,1,1,1,2,2,3, 0,0,0,0,0,1,1,1,1,2,2,2,3,3,4};
__device__ __constant__ int   d_PWB[35] = {0, 0,1,0, 0,1,2,0,1,0, 0,1,2,3,0,1,2,0,1,0, 0,1,2,3,4,0,1,2,3,0,1,2,0,1,0};
__device__ __constant__ int   d_PWC[35] = {0, 1,0,0, 2,1,0,1,0,0, 3,2,1,0,2,1,0,1,0,0, 4,3,2,1,0,3,2,1,0,2,1,0,1,0,0};
__device__ __constant__ float d_NM[35]  = {1.f, 1.f,1.f,1.f, 1.f,2.f,1.f,2.f,2.f,1.f,
                                           1.f,3.f,3.f,1.f,3.f,6.f,3.f,3.f,3.f,1.f,
                                           1.f,4.f,6.f,4.f,1.f,4.f,12.f,12.f,4.f,6.f,12.f,6.f,4.f,4.f,1.f};
__device__ __constant__ int   d_LBLK[35]= {0, 1,1,1, 2,2,2,2,2,2, 3,3,3,3,3,3,3,3,3,3, 4,4,4,4,4,4,4,4,4,4,4,4,4,4,4};
__device__ __constant__ int   d_L6[6]   = {0,1,4,10,20,35};

__device__ __forceinline__ float siluf(float x) { return x / (1.0f + __expf(-x)); }

__device__ __forceinline__ float psel(float x, int p) {
  float x2 = x * x;
  float r = 1.0f;
  r = (p == 1) ? x : r;
  r = (p == 2) ? x2 : r;
  r = (p == 3) ? x2 * x : r;
  r = (p == 4) ? x2 * x2 : r;
  return r;
}

// ---------------- k_init: zero bin counters, species embedding ----------------
__global__ void k_init(const float* __restrict__ Ws1, const float* __restrict__ bs1,
                       const float* __restrict__ Ws2, const float* __restrict__ bs2,
                       float* __restrict__ ws)
{
  int tid = blockIdx.x * blockDim.x + threadIdx.x;
  int* cnt = (int*)(ws + WS_CNT);
  if (tid < NBINS) cnt[tid] = 0;
  if (tid < 12) {
    int t = tid >> 2, s = tid & 3;
    float acc = bs2[s];
    for (int j = 0; j < 16; j++) acc += tanhf(Ws1[t * 16 + j] + bs1[j]) * Ws2[j * 4 + s];
    ws[WS_SEMB + tid] = acc;
  }
}

// ---------------- k_hist: histogram over (atom,species) bins ----------------
__global__ void k_hist(const int* __restrict__ first_atom, const int* __restrict__ second_atom,
                       const int* __restrict__ species, float* __restrict__ ws)
{
  int e = blockIdx.x * blockDim.x + threadIdx.x;
  if (e < NEDGES) {
    int* cnt = (int*)(ws + WS_CNT);
    int bin = first_atom[e] * 4 + species[second_atom[e]];
    atomicAdd(&cnt[bin], 1);
  }
}

// ---------------- k_scan: single-block scan over NBINS ----------------
__global__ __launch_bounds__(1024) void k_scan(float* __restrict__ ws)
{
  const int* cnt = (const int*)(ws + WS_CNT);
  int* offs   = (int*)(ws + WS_OFFS);
  int* cursor = (int*)(ws + WS_CURSOR);
  __shared__ int wsum[16];
  int tid = threadIdx.x;
  int lane = tid & 63, wv = tid >> 6;
  const int PER = (NBINS + 1023) / 1024;   // 40
  int lo = tid * PER;
  int hi = lo + PER; if (hi > NBINS) hi = NBINS;
  int s = 0;
  for (int i = lo; i < hi; i++) s += cnt[i];
  int inc = s;
  #pragma unroll
  for (int d = 1; d < 64; d <<= 1) {
    int v = __shfl_up(inc, d, 64);
    if (lane >= d) inc += v;
  }
  if (lane == 63) wsum[wv] = inc;
  __syncthreads();
  int woff = 0;
  for (int w = 0; w < wv; w++) woff += wsum[w];
  int run = woff + inc - s;               // exclusive prefix
  for (int i = lo; i < hi; i++) { int c = cnt[i]; offs[i] = run; cursor[i] = run; run += c; }
  if (tid == 1023) offs[NBINS] = run;
}

// ---------------- k_edge: dense per-edge MLP, scatter to (atom,species)-sorted slot ----------------
__global__ __launch_bounds__(256) void k_edge(
    const float* __restrict__ rij, const int* __restrict__ species,
    const int* __restrict__ first_atom, const int* __restrict__ second_atom,
    const float* __restrict__ Wr1, const float* __restrict__ br1,
    const float* __restrict__ Wr2, const float* __restrict__ br2,
    float* __restrict__ ws)
{
  int e = blockIdx.x * 256 + threadIdx.x;
  if (e >= NEDGES) return;
  int* cursor = (int*)(ws + WS_CURSOR);
  float* stage = ws + WS_STAGE;

  // issue gather chain + atomic early so its latency overlaps the MLP
  int a = first_atom[e];
  int t = species[second_atom[e]];
  int pos = atomicAdd(&cursor[a * 4 + t], 1);

  float x = rij[e * 3 + 0], y = rij[e * 3 + 1], z = rij[e * 3 + 2];
  float d = sqrtf(x * x + y * y + z * z + 1e-12f);
  float invd = 1.0f / d;
  float fc = (d < RC_F) ? 0.5f * (__cosf(PI_F * d / RC_F) + 1.0f) : 0.0f;

  float bes[8];
  float sq = sqrtf(2.0f / RC_F);
  #pragma unroll
  for (int k = 0; k < 8; k++) bes[k] = sq * __sinf((float)(k + 1) * (PI_F / RC_F) * d) * invd;

  // layer 1: 8 -> 64.  Wr1 [k=8][j=64], wave-uniform index -> s_load
  float h1[64];
  #pragma unroll
  for (int j4 = 0; j4 < 16; j4++) {
    float acc[4];
    #pragma unroll
    for (int u = 0; u < 4; u++) acc[u] = br1[j4 * 4 + u];
    #pragma unroll
    for (int k = 0; k < 8; k++) {
      #pragma unroll
      for (int u = 0; u < 4; u++) acc[u] += bes[k] * Wr1[k * 64 + j4 * 4 + u];
    }
    #pragma unroll
    for (int u = 0; u < 4; u++) h1[j4 * 4 + u] = siluf(acc[u]);
  }

  float* eb = stage + (size_t)pos * 52;

  // layer 2: 64 -> 48.  Wr2 [k=64][j2=48], wave-uniform index -> s_load
  for (int j4 = 0; j4 < 12; j4++) {
    float acc[4];
    #pragma unroll
    for (int u = 0; u < 4; u++) acc[u] = br2[j4 * 4 + u];
    #pragma unroll
    for (int k = 0; k < 64; k++) {
      #pragma unroll
      for (int u = 0; u < 4; u++) acc[u] += h1[k] * Wr2[k * 48 + j4 * 4 + u];
    }
    float v0 = siluf(acc[0]) * fc, v1 = siluf(acc[1]) * fc;
    float v2 = siluf(acc[2]) * fc, v3 = siluf(acc[3]) * fc;
    *(float4*)(eb + j4 * 4) = make_float4(v0, v1, v2, v3);
  }
  *(float4*)(eb + 48) = make_float4(x * invd, y * invd, z * invd, 0.0f);
}

// ---------------- k_atom: ONE WAVE PER ATOM, no __syncthreads ----------------
// lane<35: owns component c; lanes 35..42: own radial dir r for the l=0 block.
// Species runs are contiguous (sorted), so t is a compile-time index per loop.
__global__ __launch_bounds__(256) void k_atom(
    const float* __restrict__ ws,
    const float* __restrict__ Wa1, const float* __restrict__ ba1,
    const float* __restrict__ Wa2, const float* __restrict__ ba2,
    const float* __restrict__ Wa3, const float* __restrict__ ba3,
    float* __restrict__ out)
{
  // per-wave scratch: [0..863] G[t][r][36] (col 35 holds G0), [864..1055] feat, [1056..1119] h
  __shared__ __align__(16) float sScr[4][1152];
  int tid = threadIdx.x;
  int lane = tid & 63, wv = tid >> 6;
  int a = blockIdx.x * 4 + wv;            // NATOMS = 2500*4 exact
  float* sG   = &sScr[wv][0];
  float* sFeat= &sScr[wv][864];
  float* sH   = &sScr[wv][1056];

  const int* offs = (const int*)(ws + WS_OFFS);
  const float* stage = ws + WS_STAGE;
  int o0 = offs[4 * a], o1 = offs[4 * a + 1], o2 = offs[4 * a + 2], o3 = offs[4 * a + 3];

  const int c = lane;
  bool isc = (c < 35);
  int pa = 0, pb = 0, pcw = 0, lb = 0;
  if (isc) { pa = d_PWA[c]; pb = d_PWB[c]; pcw = d_PWC[c]; lb = d_LBLK[c]; }
  int rdir = lane - 35;
  bool isd = (rdir >= 0) && (rdir < 8);

  float gc[3][8];
  #pragma unroll
  for (int t2 = 0; t2 < 3; t2++)
    #pragma unroll
    for (int r = 0; r < 8; r++) gc[t2][r] = 0.0f;
  float g0[3] = {0.0f, 0.0f, 0.0f};

#define RUN(T, LO, HI)                                                        \
  for (int i = (LO); i < (HI); ++i) {                                         \
    const float* eb = stage + (size_t)i * 52;                                 \
    if (isc) {                                                                \
      float4 rt = *(const float4*)(eb + 48);                                  \
      float comp = psel(rt.x, pa) * psel(rt.y, pb) * psel(rt.z, pcw);         \
      float4 Ra = *(const float4*)(eb + 8 + 8 * lb);                          \
      float4 Rb = *(const float4*)(eb + 12 + 8 * lb);                         \
      gc[T][0] += comp * Ra.x; gc[T][1] += comp * Ra.y;                       \
      gc[T][2] += comp * Ra.z; gc[T][3] += comp * Ra.w;                       \
      gc[T][4] += comp * Rb.x; gc[T][5] += comp * Rb.y;                       \
      gc[T][6] += comp * Rb.z; gc[T][7] += comp * Rb.w;                       \
    } else if (isd) {                                                         \
      g0[T] += eb[rdir];                                                      \
    }                                                                         \
  }

  RUN(0, o0, o1)
  RUN(1, o1, o2)
  RUN(2, o2, o3)
#undef RUN

  // transpose G into LDS (same-wave, no barrier needed)
  if (isc) {
    #pragma unroll
    for (int t2 = 0; t2 < 3; t2++)
      #pragma unroll
      for (int r = 0; r < 8; r++) sG[(t2 * 8 + r) * 36 + c] = gc[t2][r];
  } else if (isd) {
    #pragma unroll
    for (int t2 = 0; t2 < 3; t2++) sG[(t2 * 8 + rdir) * 36 + 35] = g0[t2];
  }

  // contraction: lane owns feats {lane, lane+64, lane+128}; feat idx f=(blk*8+rr)*4+s
  int s = lane & 3;
  float se0 = ws[WS_SEMB + s], se1 = ws[WS_SEMB + 4 + s], se2 = ws[WS_SEMB + 8 + s];
  float fout[3];
  #pragma unroll
  for (int u = 0; u < 3; u++) {
    int f = lane + 64 * u;
    int blk = f >> 5, rr = (f >> 2) & 7;
    float acc;
    if (blk == 0) {
      acc = se0 * sG[(0 + rr) * 36 + 35] + se1 * sG[(8 + rr) * 36 + 35] + se2 * sG[(16 + rr) * 36 + 35];
    } else {
      int c0 = d_L6[blk - 1], c1 = d_L6[blk];
      acc = 0.0f;
      for (int cc = c0; cc < c1; cc++) {
        float A = se0 * sG[(0 + rr) * 36 + cc] + se1 * sG[(8 + rr) * 36 + cc] + se2 * sG[(16 + rr) * 36 + cc];
        acc += d_NM[cc] * A * A;
      }
    }
    fout[u] = acc;
  }
  #pragma unroll
  for (int u = 0; u < 3; u++) sFeat[lane + 64 * u] = fout[u];

  // MLP layer 1: 192 -> 64.  feat broadcast from LDS, Wa1 [k][j] coalesced over lanes.
  {
    float a0 = 0.f, a1 = 0.f, a2 = 0.f, a3 = 0.f;
    for (int k4 = 0; k4 < 48; k4++) {
      float4 f4 = *(const float4*)(sFeat + k4 * 4);
      const float* w = Wa1 + (k4 * 4) * 64 + lane;
      a0 += f4.x * w[0];
      a1 += f4.y * w[64];
      a2 += f4.z * w[128];
      a3 += f4.w * w[192];
    }
    sH[lane] = siluf(a0 + a1 + a2 + a3 + ba1[lane]);
  }

  // MLP layer 2: 64 -> 64, then layer 3 + wave reduction
  {
    float a0 = 0.f, a1 = 0.f, a2 = 0.f, a3 = 0.f;
    for (int k4 = 0; k4 < 16; k4++) {
      float4 h4 = *(const float4*)(sH + k4 * 4);
      const float* w = Wa2 + (k4 * 4) * 64 + lane;
      a0 += h4.x * w[0];
      a1 += h4.y * w[64];
      a2 += h4.z * w[128];
      a3 += h4.w * w[192];
    }
    float h2 = siluf(a0 + a1 + a2 + a3 + ba2[lane]);
    float pr = h2 * Wa3[lane];
    #pragma unroll
    for (int off = 32; off > 0; off >>= 1) pr += __shfl_down(pr, off, 64);
    if (lane == 0) out[a] = pr + ba3[0];
  }
}

extern "C" void kernel_launch(void* const* d_in, const int* in_sizes, int n_in,
                              void* d_out, int out_size, void* d_ws, size_t ws_size,
                              hipStream_t stream)
{
  const float* rij         = (const float*)d_in[0];
  const int*   species     = (const int*)  d_in[1];
  const int*   first_atom  = (const int*)  d_in[2];
  const int*   second_atom = (const int*)  d_in[3];
  const float* Wr1 = (const float*)d_in[4];
  const float* br1 = (const float*)d_in[5];
  const float* Wr2 = (const float*)d_in[6];
  const float* br2 = (const float*)d_in[7];
  const float* Ws1 = (const float*)d_in[8];
  const float* bs1 = (const float*)d_in[9];
  const float* Ws2 = (const float*)d_in[10];
  const float* bs2 = (const float*)d_in[11];
  const float* Wa1 = (const float*)d_in[12];
  const float* ba1 = (const float*)d_in[13];
  const float* Wa2 = (const float*)d_in[14];
  const float* ba2 = (const float*)d_in[15];
  const float* Wa3 = (const float*)d_in[16];
  const float* ba3 = (const float*)d_in[17];
  float* ws  = (float*)d_ws;
  float* out = (float*)d_out;

  k_init<<<(NBINS + 255) / 256, 256, 0, stream>>>(Ws1, bs1, Ws2, bs2, ws);
  k_hist<<<(NEDGES + 255) / 256, 256, 0, stream>>>(first_atom, second_atom, species, ws);
  k_scan<<<1, 1024, 0, stream>>>(ws);
  k_edge<<<(NEDGES + 255) / 256, 256, 0, stream>>>(rij, species, first_atom, second_atom,
                                                   Wr1, br1, Wr2, br2, ws);
  k_atom<<<NATOMS / 4, 256, 0, stream>>>(ws, Wa1, ba1, Wa2, ba2, Wa3, ba3, out);
}

// Round 4
// 255.234 us; speedup vs baseline: 2.1130x; 1.3428x over previous
//
#include <hip/hip_runtime.h>
#include <math.h>

#define NATOMS 10000
#define NEDGES 320000
#define NBINS  (NATOMS * 4)     // bin = atom*4 + species (bin a*4+3 always empty)
#define RC_F 5.0f
#define PI_F 3.14159265358979323846f

// ---- workspace layout (in floats; all段 16B-aligned) ----
#define WS_SEMB   0         // 12 floats: semb[t][s]
#define WS_GTOT   12        // 1 int: global allocation cursor
#define WS_CNT    16        // NBINS ints
#define WS_OFFS   40016     // NBINS ints (offs[4a+3] = end of atom a's run)
#define WS_CURSOR 80016     // NBINS ints
#define WS_STAGE  120016    // NEDGES*52 floats (stride 208B)

// multinomial term tables (global component index 0..34)
__device__ __constant__ int   d_PWA[35] = {0, 0,0,1, 0,0,0,1,1,2, 0,0,0,0,1,1,1,2,2,3, 0,0,0,0,0,1,1,1,1,2,2,2,3,3,4};
__device__ __constant__ int   d_PWB[35] = {0, 0,1,0, 0,1,2,0,1,0, 0,1,2,3,0,1,2,0,1,0, 0,1,2,3,4,0,1,2,3,0,1,2,0,1,0};
__device__ __constant__ int   d_PWC[35] = {0, 1,0,0, 2,1,0,1,0,0, 3,2,1,0,2,1,0,1,0,0, 4,3,2,1,0,3,2,1,0,2,1,0,1,0,0};
__device__ __constant__ float d_NM[35]  = {1.f, 1.f,1.f,1.f, 1.f,2.f,1.f,2.f,2.f,1.f,
                                           1.f,3.f,3.f,1.f,3.f,6.f,3.f,3.f,3.f,1.f,
                                           1.f,4.f,6.f,4.f,1.f,4.f,12.f,12.f,4.f,6.f,12.f,6.f,4.f,4.f,1.f};
__device__ __constant__ int   d_LBLK[35]= {0, 1,1,1, 2,2,2,2,2,2, 3,3,3,3,3,3,3,3,3,3, 4,4,4,4,4,4,4,4,4,4,4,4,4,4,4};
__device__ __constant__ int   d_L6[6]   = {0,1,4,10,20,35};

__device__ __forceinline__ float siluf(float x) { return x / (1.0f + __expf(-x)); }

__device__ __forceinline__ float psel(float x, int p) {
  float x2 = x * x;
  float r = 1.0f;
  r = (p == 1) ? x : r;
  r = (p == 2) ? x2 : r;
  r = (p == 3) ? x2 * x : r;
  r = (p == 4) ? x2 * x2 : r;
  return r;
}

// ---------------- k_init: zero bin counters + global cursor, species embedding ----------------
__global__ void k_init(const float* __restrict__ Ws1, const float* __restrict__ bs1,
                       const float* __restrict__ Ws2, const float* __restrict__ bs2,
                       float* __restrict__ ws)
{
  int tid = blockIdx.x * blockDim.x + threadIdx.x;
  int* cnt = (int*)(ws + WS_CNT);
  if (tid < NBINS) cnt[tid] = 0;
  if (tid == 0) *(int*)(ws + WS_GTOT) = 0;
  if (tid < 12) {
    int t = tid >> 2, s = tid & 3;
    float acc = bs2[s];
    for (int j = 0; j < 16; j++) acc += tanhf(Ws1[t * 16 + j] + bs1[j]) * Ws2[j * 4 + s];
    ws[WS_SEMB + tid] = acc;
  }
}

// ---------------- k_hist: histogram over (atom,species) bins ----------------
__global__ void k_hist(const int* __restrict__ first_atom, const int* __restrict__ second_atom,
                       const int* __restrict__ species, float* __restrict__ ws)
{
  int e = blockIdx.x * blockDim.x + threadIdx.x;
  if (e < NEDGES) {
    int* cnt = (int*)(ws + WS_CNT);
    int bin = first_atom[e] * 4 + species[second_atom[e]];
    atomicAdd(&cnt[bin], 1);
  }
}

// ---------------- k_alloc: decentralized slot allocation (order-free "scan") ----------------
// One atom per thread. Per-block exclusive scan of per-atom edge totals, one global
// atomicAdd per block for the base. Allocation order across blocks is nondeterministic
// but forms a valid partition; k_atom only needs each atom's 4 runs contiguous.
__global__ __launch_bounds__(256) void k_alloc(float* __restrict__ ws)
{
  const int4* cnt4 = (const int4*)(ws + WS_CNT);
  int4* offs4   = (int4*)(ws + WS_OFFS);
  int4* cursor4 = (int4*)(ws + WS_CURSOR);
  int* gtot = (int*)(ws + WS_GTOT);
  __shared__ int wsum[4];
  __shared__ int sbase;
  int tid = threadIdx.x;
  int lane = tid & 63, wv = tid >> 6;
  int a = blockIdx.x * 256 + tid;
  bool live = (a < NATOMS);
  int4 c = live ? cnt4[a] : make_int4(0, 0, 0, 0);
  int s = c.x + c.y + c.z + c.w;          // c.w == 0 always
  int inc = s;
  #pragma unroll
  for (int d = 1; d < 64; d <<= 1) {
    int v = __shfl_up(inc, d, 64);
    if (lane >= d) inc += v;
  }
  if (lane == 63) wsum[wv] = inc;
  __syncthreads();
  if (tid == 0) {
    int btot = wsum[0] + wsum[1] + wsum[2] + wsum[3];
    sbase = atomicAdd(gtot, btot);
  }
  __syncthreads();
  int woff = sbase;
  for (int w = 0; w < wv; w++) woff += wsum[w];
  int o0 = woff + inc - s;                // exclusive prefix for this atom
  if (live) {
    int4 o;
    o.x = o0;
    o.y = o.x + c.x;
    o.z = o.y + c.y;
    o.w = o.z + c.z;                      // end of atom's run
    offs4[a] = o;
    cursor4[a] = o;
  }
}

// ---------------- k_edge: dense per-edge MLP, scatter to (atom,species)-sorted slot ----------------
__global__ __launch_bounds__(256) void k_edge(
    const float* __restrict__ rij, const int* __restrict__ species,
    const int* __restrict__ first_atom, const int* __restrict__ second_atom,
    const float* __restrict__ Wr1, const float* __restrict__ br1,
    const float* __restrict__ Wr2, const float* __restrict__ br2,
    float* __restrict__ ws)
{
  int e = blockIdx.x * 256 + threadIdx.x;
  if (e >= NEDGES) return;
  int* cursor = (int*)(ws + WS_CURSOR);
  float* stage = ws + WS_STAGE;

  // issue gather chain + atomic early so its latency overlaps the MLP
  int a = first_atom[e];
  int t = species[second_atom[e]];
  int pos = atomicAdd(&cursor[a * 4 + t], 1);

  float x = rij[e * 3 + 0], y = rij[e * 3 + 1], z = rij[e * 3 + 2];
  float d = sqrtf(x * x + y * y + z * z + 1e-12f);
  float invd = 1.0f / d;
  float fc = (d < RC_F) ? 0.5f * (__cosf(PI_F * d / RC_F) + 1.0f) : 0.0f;

  float bes[8];
  float sq = sqrtf(2.0f / RC_F);
  #pragma unroll
  for (int k = 0; k < 8; k++) bes[k] = sq * __sinf((float)(k + 1) * (PI_F / RC_F) * d) * invd;

  // layer 1: 8 -> 64.  Wr1 [k=8][j=64], wave-uniform index -> s_load
  float h1[64];
  #pragma unroll
  for (int j4 = 0; j4 < 16; j4++) {
    float acc[4];
    #pragma unroll
    for (int u = 0; u < 4; u++) acc[u] = br1[j4 * 4 + u];
    #pragma unroll
    for (int k = 0; k < 8; k++) {
      #pragma unroll
      for (int u = 0; u < 4; u++) acc[u] += bes[k] * Wr1[k * 64 + j4 * 4 + u];
    }
    #pragma unroll
    for (int u = 0; u < 4; u++) h1[j4 * 4 + u] = siluf(acc[u]);
  }

  float* eb = stage + (size_t)pos * 52;

  // layer 2: 64 -> 48.  Wr2 [k=64][j2=48], wave-uniform index -> s_load
  for (int j4 = 0; j4 < 12; j4++) {
    float acc[4];
    #pragma unroll
    for (int u = 0; u < 4; u++) acc[u] = br2[j4 * 4 + u];
    #pragma unroll
    for (int k = 0; k < 64; k++) {
      #pragma unroll
      for (int u = 0; u < 4; u++) acc[u] += h1[k] * Wr2[k * 48 + j4 * 4 + u];
    }
    float v0 = siluf(acc[0]) * fc, v1 = siluf(acc[1]) * fc;
    float v2 = siluf(acc[2]) * fc, v3 = siluf(acc[3]) * fc;
    *(float4*)(eb + j4 * 4) = make_float4(v0, v1, v2, v3);
  }
  *(float4*)(eb + 48) = make_float4(x * invd, y * invd, z * invd, 0.0f);
}

// ---------------- k_atom: ONE WAVE PER ATOM, no __syncthreads ----------------
// lane<35: owns component c; lanes 35..42: own radial dir r for the l=0 block.
// Species runs are contiguous (sorted), so t is a compile-time index per loop.
__global__ __launch_bounds__(256) void k_atom(
    const float* __restrict__ ws,
    const float* __restrict__ Wa1, const float* __restrict__ ba1,
    const float* __restrict__ Wa2, const float* __restrict__ ba2,
    const float* __restrict__ Wa3, const float* __restrict__ ba3,
    float* __restrict__ out)
{
  // per-wave scratch: [0..863] G[t][r][36] (col 35 holds G0), [864..1055] feat, [1056..1119] h
  __shared__ __align__(16) float sScr[4][1152];
  int tid = threadIdx.x;
  int lane = tid & 63, wv = tid >> 6;
  int a = blockIdx.x * 4 + wv;            // NATOMS = 2500*4 exact
  float* sG   = &sScr[wv][0];
  float* sFeat= &sScr[wv][864];
  float* sH   = &sScr[wv][1056];

  const int* offs = (const int*)(ws + WS_OFFS);
  const float* stage = ws + WS_STAGE;
  int o0 = offs[4 * a], o1 = offs[4 * a + 1], o2 = offs[4 * a + 2], o3 = offs[4 * a + 3];

  const int c = lane;
  bool isc = (c < 35);
  int pa = 0, pb = 0, pcw = 0, lb = 0;
  if (isc) { pa = d_PWA[c]; pb = d_PWB[c]; pcw = d_PWC[c]; lb = d_LBLK[c]; }
  int rdir = lane - 35;
  bool isd = (rdir >= 0) && (rdir < 8);

  float gc[3][8];
  #pragma unroll
  for (int t2 = 0; t2 < 3; t2++)
    #pragma unroll
    for (int r = 0; r < 8; r++) gc[t2][r] = 0.0f;
  float g0[3] = {0.0f, 0.0f, 0.0f};

#define RUN(T, LO, HI)                                                        \
  for (int i = (LO); i < (HI); ++i) {                                         \
    const float* eb = stage + (size_t)i * 52;                                 \
    if (isc) {                                                                \
      float4 rt = *(const float4*)(eb + 48);                                  \
      float comp = psel(rt.x, pa) * psel(rt.y, pb) * psel(rt.z, pcw);         \
      float4 Ra = *(const float4*)(eb + 8 + 8 * lb);                          \
      float4 Rb = *(const float4*)(eb + 12 + 8 * lb);                         \
      gc[T][0] += comp * Ra.x; gc[T][1] += comp * Ra.y;                       \
      gc[T][2] += comp * Ra.z; gc[T][3] += comp * Ra.w;                       \
      gc[T][4] += comp * Rb.x; gc[T][5] += comp * Rb.y;                       \
      gc[T][6] += comp * Rb.z; gc[T][7] += comp * Rb.w;                       \
    } else if (isd) {                                                         \
      g0[T] += eb[rdir];                                                      \
    }                                                                         \
  }

  RUN(0, o0, o1)
  RUN(1, o1, o2)
  RUN(2, o2, o3)
#undef RUN

  // transpose G into LDS (same-wave, no barrier needed)
  if (isc) {
    #pragma unroll
    for (int t2 = 0; t2 < 3; t2++)
      #pragma unroll
      for (int r = 0; r < 8; r++) sG[(t2 * 8 + r) * 36 + c] = gc[t2][r];
  } else if (isd) {
    #pragma unroll
    for (int t2 = 0; t2 < 3; t2++) sG[(t2 * 8 + rdir) * 36 + 35] = g0[t2];
  }

  // contraction: lane owns feats {lane, lane+64, lane+128}; feat idx f=(blk*8+rr)*4+s
  int s = lane & 3;
  float se0 = ws[WS_SEMB + s], se1 = ws[WS_SEMB + 4 + s], se2 = ws[WS_SEMB + 8 + s];
  float fout[3];
  #pragma unroll
  for (int u = 0; u < 3; u++) {
    int f = lane + 64 * u;
    int blk = f >> 5, rr = (f >> 2) & 7;
    float acc;
    if (blk == 0) {
      acc = se0 * sG[(0 + rr) * 36 + 35] + se1 * sG[(8 + rr) * 36 + 35] + se2 * sG[(16 + rr) * 36 + 35];
    } else {
      int c0 = d_L6[blk - 1], c1 = d_L6[blk];
      acc = 0.0f;
      for (int cc = c0; cc < c1; cc++) {
        float A = se0 * sG[(0 + rr) * 36 + cc] + se1 * sG[(8 + rr) * 36 + cc] + se2 * sG[(16 + rr) * 36 + cc];
        acc += d_NM[cc] * A * A;
      }
    }
    fout[u] = acc;
  }
  #pragma unroll
  for (int u = 0; u < 3; u++) sFeat[lane + 64 * u] = fout[u];

  // MLP layer 1: 192 -> 64.  feat broadcast from LDS, Wa1 [k][j] coalesced over lanes.
  {
    float a0 = 0.f, a1 = 0.f, a2 = 0.f, a3 = 0.f;
    for (int k4 = 0; k4 < 48; k4++) {
      float4 f4 = *(const float4*)(sFeat + k4 * 4);
      const float* w = Wa1 + (k4 * 4) * 64 + lane;
      a0 += f4.x * w[0];
      a1 += f4.y * w[64];
      a2 += f4.z * w[128];
      a3 += f4.w * w[192];
    }
    sH[lane] = siluf(a0 + a1 + a2 + a3 + ba1[lane]);
  }

  // MLP layer 2: 64 -> 64, then layer 3 + wave reduction
  {
    float a0 = 0.f, a1 = 0.f, a2 = 0.f, a3 = 0.f;
    for (int k4 = 0; k4 < 16; k4++) {
      float4 h4 = *(const float4*)(sH + k4 * 4);
      const float* w = Wa2 + (k4 * 4) * 64 + lane;
      a0 += h4.x * w[0];
      a1 += h4.y * w[64];
      a2 += h4.z * w[128];
      a3 += h4.w * w[192];
    }
    float h2 = siluf(a0 + a1 + a2 + a3 + ba2[lane]);
    float pr = h2 * Wa3[lane];
    #pragma unroll
    for (int off = 32; off > 0; off >>= 1) pr += __shfl_down(pr, off, 64);
    if (lane == 0) out[a] = pr + ba3[0];
  }
}

extern "C" void kernel_launch(void* const* d_in, const int* in_sizes, int n_in,
                              void* d_out, int out_size, void* d_ws, size_t ws_size,
                              hipStream_t stream)
{
  const float* rij         = (const float*)d_in[0];
  const int*   species     = (const int*)  d_in[1];
  const int*   first_atom  = (const int*)  d_in[2];
  const int*   second_atom = (const int*)  d_in[3];
  const float* Wr1 = (const float*)d_in[4];
  const float* br1 = (const float*)d_in[5];
  const float* Wr2 = (const float*)d_in[6];
  const float* br2 = (const float*)d_in[7];
  const float* Ws1 = (const float*)d_in[8];
  const float* bs1 = (const float*)d_in[9];
  const float* Ws2 = (const float*)d_in[10];
  const float* bs2 = (const float*)d_in[11];
  const float* Wa1 = (const float*)d_in[12];
  const float* ba1 = (const float*)d_in[13];
  const float* Wa2 = (const float*)d_in[14];
  const float* ba2 = (const float*)d_in[15];
  const float* Wa3 = (const float*)d_in[16];
  const float* ba3 = (const float*)d_in[17];
  float* ws  = (float*)d_ws;
  float* out = (float*)d_out;

  k_init<<<(NBINS + 255) / 256, 256, 0, stream>>>(Ws1, bs1, Ws2, bs2, ws);
  k_hist<<<(NEDGES + 255) / 256, 256, 0, stream>>>(first_atom, second_atom, species, ws);
  k_alloc<<<(NATOMS + 255) / 256, 256, 0, stream>>>(ws);
  k_edge<<<(NEDGES + 255) / 256, 256, 0, stream>>>(rij, species, first_atom, second_atom,
                                                   Wr1, br1, Wr2, br2, ws);
  k_atom<<<NATOMS / 4, 256, 0, stream>>>(ws, Wa1, ba1, Wa2, ba2, Wa3, ba3, out);
}